// Round 2
// baseline (225.765 us; speedup 1.0000x reference)
//
#include <hip/hip_runtime.h>
#include <stdint.h>

#define Bn  8
#define LQn 2048
#define LKn 2048
#define Dn  512
#define NT  64            // 2048 / KVBLK
#define KVB 32

using f32x4  = __attribute__((ext_vector_type(4))) float;
using bf16x8 = __attribute__((ext_vector_type(8))) __bf16;
using u16x4  = __attribute__((ext_vector_type(4))) unsigned short;
using u16x8  = __attribute__((ext_vector_type(8))) unsigned short;

#define WS_MASK_OFF 256
#define WS_K_OFF    (WS_MASK_OFF + Bn*LKn*4)
#define WS_VT_OFF   (WS_K_OFF + Bn*LKn*Dn*2)
#define WS_REQ      ((size_t)WS_VT_OFF + (size_t)Bn*LKn*Dn*2)

union BFU { __bf16 h; unsigned short u; };
static __device__ __forceinline__ unsigned short f2bfu(float x) { BFU t; t.h = (__bf16)x; return t.u; }

static __device__ __forceinline__ void gload16(const void* g, void* l) {
  __builtin_amdgcn_global_load_lds((const __attribute__((address_space(1))) void*)g,
                                   (__attribute__((address_space(3))) void*)l,
                                   16, 0, 0);
}

// ---- mask dtype detect + additive-mask build (single block) ----
__global__ void mask_prep_kernel(const void* __restrict__ mraw, float* __restrict__ maskadd) {
  __shared__ int sBig, sOff;
  const int tid = threadIdx.x;
  if (tid == 0) { sBig = 0; sOff = 0; }
  __syncthreads();
  const unsigned char* mb = (const unsigned char*)mraw;
  int big = 0, off = 0;
  for (int i = tid; i < Bn*LKn; i += blockDim.x) {
    unsigned char v = mb[i];
    big |= (v > 1) ? 1 : 0;
    off |= (((i & 3) != 0) && v != 0) ? 1 : 0;
  }
  if (big) atomicOr(&sBig, 1);
  if (off) atomicOr(&sOff, 1);
  __syncthreads();
  const int f = sBig ? 2 : (sOff ? 1 : 0);
  for (int i = tid; i < Bn*LKn; i += blockDim.x) {
    bool m;
    if (f == 2)      m = ((const float*)mraw)[i] != 0.0f;
    else if (f == 1) m = mb[i] != 0;
    else             m = ((const int*)mraw)[i] != 0;
    maskadd[i] = m ? -1e30f : 0.0f;
  }
}

// ---- K fp32 -> bf16 ----
__global__ void conv_k_kernel(const float* __restrict__ src, unsigned short* __restrict__ dst) {
  int i = blockIdx.x * blockDim.x + threadIdx.x;
  const f32x4* s4 = (const f32x4*)src + (size_t)i * 2;
  f32x4 a = s4[0], b = s4[1];
  u16x8 o;
#pragma unroll
  for (int j = 0; j < 4; ++j) { o[j] = f2bfu(a[j]); o[j+4] = f2bfu(b[j]); }
  *((u16x8*)dst + i) = o;
}

// ---- V fp32 [B][LK][D] -> Vt bf16 [B][D][LK] ----
__global__ void conv_vt_kernel(const float* __restrict__ v, unsigned short* __restrict__ vt) {
  __shared__ float t[64][65];
  const int b = blockIdx.z, dt = blockIdx.y, kt = blockIdx.x;
  const float* vbase = v + ((size_t)(b*LKn) + kt*64)*Dn + dt*64;
  for (int i = threadIdx.x; i < 64*64; i += blockDim.x) {
    int kk = i >> 6, dd = i & 63;
    t[kk][dd] = vbase[(size_t)kk*Dn + dd];
  }
  __syncthreads();
  unsigned short* vtbase = vt + ((size_t)(b*Dn) + dt*64)*LKn + kt*64;
  for (int i = threadIdx.x; i < 64*16; i += blockDim.x) {
    int dd = i >> 4, kg = (i & 15) * 4;
    u16x4 o;
#pragma unroll
    for (int j = 0; j < 4; ++j) o[j] = f2bfu(t[kg+j][dd]);
    *(u16x4*)(vtbase + (size_t)dd*LKn + kg) = o;
  }
}

// staging helpers (wave-linear gload_lds dest, pre-swizzled global src)
static __device__ __forceinline__ void stage_k(const char* kg, char* klbase, int t, int w, int lane) {
  const char* gb = kg + (size_t)t * (KVB*1024);
#pragma unroll
  for (int j = 0; j < 4; ++j)
    gload16(gb + (size_t)((j*8 + w) * 1024) + ((lane ^ w) << 4),
            klbase + (j*8 + w) * 1024);
}
static __device__ __forceinline__ void stage_v(const char* vg, char* vlbase, int t, int w, int lane) {
  const char* gb = vg + (size_t)t * (KVB*2);
  char* lb = vlbase + w*1024;
  const int srcs = ((lane & 3) ^ ((lane >> 3) & 3)) << 4;
#pragma unroll
  for (int j = 0; j < 4; ++j) {
    const int d = j*128 + w*16 + (lane >> 2);
    gload16(gb + (size_t)d*4096 + srcs, lb + j*8192);
  }
}

// ---- flash attention: QBLK=64, KVBLK=32, 8 waves, dbuf K+V, 2 barriers/iter ----
__launch_bounds__(512, 2)
__global__ void attn_kernel(const float* __restrict__ q, const unsigned short* __restrict__ kb,
                            const unsigned short* __restrict__ vtb,
                            const float* __restrict__ ratio, const float* __restrict__ scalep,
                            const float* __restrict__ maskadd, float* __restrict__ out) {
  __shared__ __align__(16) unsigned short Kl[2][KVB*512];   // 64 KiB  chunk c=key*64+(slot^(key&7))
  __shared__ __align__(16) unsigned short Vl[2][512*KVB];   // 64 KiB  chunk c=d*4+(slot^((d>>1)&3))
  __shared__ __align__(16) unsigned short Pl[64*KVB];       // 4 KiB   chunk c=q*4+(slot^((q>>1)&3))
  __shared__ __align__(16) float maskl2[LKn];               // 8 KiB
  __shared__ float redm2[64][2];
  __shared__ float reds2[64][2];
  __shared__ float facl[64];
  __shared__ float linvl[64];
  __shared__ int   sflag[2];

  const int tid = threadIdx.x;
  const int w = tid >> 6, lane = tid & 63;
  const int lane16 = lane & 15, lgrp = lane >> 4;
  const int qf = w & 3, kh = w >> 2;       // QK^T mapping: 4 q-frags x 2 key-halves
  const int bid = blockIdx.x;
  const int b = bid & 7, qtile = bid >> 3; // XCD-affine batches
  const int qbase = qtile * 64;

  const float c2 = scalep[0] * ratio[b] * 1.4426950408889634f;  // log2-domain scale

  // stage mask row (additive, log2 domain uses plain -1e30)
  *(f32x4*)&maskl2[tid*4] = *(const f32x4*)(maskadd + (size_t)b*LKn + tid*4);
  if (tid == 0) { sflag[0] = 0; sflag[1] = 0; }

  // hoist Q fragments (A: row=lane16, k = lgrp*8+j)
  bf16x8 qfrag[16];
  {
    const float* qrow = q + ((size_t)(b*LQn) + qbase + qf*16 + lane16) * Dn;
#pragma unroll
    for (int ks = 0; ks < 16; ++ks) {
      const int d0 = ks*32 + lgrp*8;
      f32x4 a = *(const f32x4*)(qrow + d0);
      f32x4 bb = *(const f32x4*)(qrow + d0 + 4);
      bf16x8 f;
#pragma unroll
      for (int j = 0; j < 4; ++j) { f[j] = (__bf16)a[j]; f[j+4] = (__bf16)bb[j]; }
      qfrag[ks] = f;
    }
  }

  f32x4 o[16];
#pragma unroll
  for (int i = 0; i < 16; ++i) { o[i][0]=0.f; o[i][1]=0.f; o[i][2]=0.f; o[i][3]=0.f; }
  float mrow[4] = {-3e38f, -3e38f, -3e38f, -3e38f};
  float lrow[4] = {0.f, 0.f, 0.f, 0.f};

  const char* kg = (const char*)kb  + (size_t)b*LKn*Dn*2;
  const char* vg = (const char*)vtb + (size_t)b*Dn*LKn*2;

  // prologue: K0, V0, K1 in flight; drain K0+V0
  stage_k(kg, (char*)Kl[0], 0, w, lane);
  stage_v(vg, (char*)Vl[0], 0, w, lane);
  stage_k(kg, (char*)Kl[1], 1, w, lane);
  asm volatile("s_waitcnt vmcnt(4) lgkmcnt(0)" ::: "memory");
  __builtin_amdgcn_s_barrier();
  asm volatile("" ::: "memory");

  const int key = kh*16 + lane16;
  const int kx7 = key & 7;
  const int vsw = (lgrp ^ ((lane16 >> 1) & 3)) << 4;

  for (int t = 0; t < NT; ++t) {
    const int cur = t & 1;
    // ---- QK^T (16 keys per wave) ----
    f32x4 s; s[0]=0.f; s[1]=0.f; s[2]=0.f; s[3]=0.f;
    const char* klp = (const char*)Kl[cur] + key*1024;
    __builtin_amdgcn_s_setprio(1);
#pragma unroll
    for (int ks = 0; ks < 16; ++ks) {
      const bf16x8 bk = *(const bf16x8*)(klp + ((((ks<<2) + lgrp) ^ kx7) << 4));
      s = __builtin_amdgcn_mfma_f32_16x16x32_bf16(qfrag[ks], bk, s, 0, 0, 0);
    }
    __builtin_amdgcn_s_setprio(0);

    const float mL = maskl2[t*KVB + key];
    float sl[4], tmax[4];
    bool needb = false;
#pragma unroll
    for (int r = 0; r < 4; ++r) {
      sl[r] = s[r]*c2 + mL;
      float v = sl[r];
      v = fmaxf(v, __shfl_xor(v, 1));
      v = fmaxf(v, __shfl_xor(v, 2));
      v = fmaxf(v, __shfl_xor(v, 4));
      v = fmaxf(v, __shfl_xor(v, 8));
      tmax[r] = v;
      needb = needb || (v > mrow[r] + 12.0f);
    }
    if (lane16 == 0) {
#pragma unroll
      for (int r = 0; r < 4; ++r) redm2[qf*16 + lgrp*4 + r][kh] = tmax[r];
    }
    if (__any(needb) && lane == 0) atomicOr(&sflag[cur], 1);

    // barrier A: V(t)+K(t+1) arrived, QK^T(t) done everywhere, redm/flag visible
    asm volatile("s_waitcnt vmcnt(0) lgkmcnt(0)" ::: "memory");
    __builtin_amdgcn_s_barrier();
    asm volatile("" ::: "memory");

    // prefetch (stays in flight across barrier B and next QK^T)
    if (t + 2 < NT) stage_k(kg, (char*)Kl[cur], t + 2, w, lane);
    if (t + 1 < NT) stage_v(vg, (char*)Vl[cur ^ 1], t + 1, w, lane);

    const int flag = sflag[cur];
    float fac[4];
    if (flag) {
#pragma unroll
      for (int r = 0; r < 4; ++r) {
        const int row = qf*16 + lgrp*4 + r;
        const float tm = fmaxf(redm2[row][0], redm2[row][1]);
        const float mn = fmaxf(mrow[r], tm);
        fac[r] = exp2f(mrow[r] - mn);
        mrow[r] = mn;
      }
      if (kh == 0 && lane16 == 0) {
#pragma unroll
        for (int r = 0; r < 4; ++r) facl[qf*16 + lgrp*4 + r] = fac[r];
      }
    }
    float pv4[4];
#pragma unroll
    for (int r = 0; r < 4; ++r) {
      pv4[r] = exp2f(sl[r] - mrow[r]);
      float v = pv4[r];
      v += __shfl_xor(v, 1); v += __shfl_xor(v, 2);
      v += __shfl_xor(v, 4); v += __shfl_xor(v, 8);
      if (lane16 == 0) reds2[qf*16 + lgrp*4 + r][kh] = v;
    }
    {  // P write (bf16, swizzled 64B rows)
      const int slot = kh*2 + (lane16 >> 3);
#pragma unroll
      for (int r = 0; r < 4; ++r) {
        const int prow = qf*16 + lgrp*4 + r;
        const int px = (prow >> 1) & 3;
        *(unsigned short*)((char*)Pl + prow*64 + ((slot ^ px) << 4) + (lane16 & 7)*2) = f2bfu(pv4[r]);
      }
    }

    // barrier B: P/reds/fac ready — NO vmcnt drain (prefetch stays in flight)
    asm volatile("s_waitcnt lgkmcnt(0)" ::: "memory");
    __builtin_amdgcn_s_barrier();
    asm volatile("" ::: "memory");
    if (tid == 0) sflag[cur] = 0;

    // O rescale (rare) + l update (owner layout)
    if (flag) {
#pragma unroll
      for (int qi = 0; qi < 4; ++qi)
#pragma unroll
        for (int r = 0; r < 4; ++r) {
          const float f = facl[qi*16 + lgrp*4 + r];
#pragma unroll
          for (int dfi = 0; dfi < 4; ++dfi) o[qi*4 + dfi][r] *= f;
        }
    }
#pragma unroll
    for (int r = 0; r < 4; ++r) {
      const int row = qf*16 + lgrp*4 + r;
      const float add = reds2[row][0] + reds2[row][1];
      lrow[r] = (flag ? lrow[r]*fac[r] : lrow[r]) + add;
    }

    // ---- PV: wave w owns 64 d-cols (V tile read exactly once block-wide) ----
    bf16x8 vbr[4];
#pragma unroll
    for (int dfi = 0; dfi < 4; ++dfi) {
      const int d = w*64 + dfi*16 + lane16;
      vbr[dfi] = *(const bf16x8*)((const char*)Vl[cur] + d*64 + vsw);
    }
    __builtin_amdgcn_s_setprio(1);
#pragma unroll
    for (int qi = 0; qi < 4; ++qi) {
      const int prow = qi*16 + lane16;
      const bf16x8 pa = *(const bf16x8*)((const char*)Pl + prow*64 + vsw);
#pragma unroll
      for (int dfi = 0; dfi < 4; ++dfi)
        o[qi*4 + dfi] = __builtin_amdgcn_mfma_f32_16x16x32_bf16(pa, vbr[dfi], o[qi*4 + dfi], 0, 0, 0);
    }
    __builtin_amdgcn_s_setprio(0);
  }

  // epilogue: redistribute 1/l, write out
  if (kh == 0 && lane16 == 0) {
#pragma unroll
    for (int r = 0; r < 4; ++r) linvl[qf*16 + lgrp*4 + r] = 1.0f / lrow[r];
  }
  asm volatile("s_waitcnt lgkmcnt(0)" ::: "memory");
  __builtin_amdgcn_s_barrier();
  asm volatile("" ::: "memory");
  float* ob = out + ((size_t)(b*LQn) + qbase)*Dn + w*64;
#pragma unroll
  for (int qi = 0; qi < 4; ++qi)
#pragma unroll
    for (int r = 0; r < 4; ++r) {
      const float li = linvl[qi*16 + lgrp*4 + r];
      float* orow = ob + (size_t)(qi*16 + lgrp*4 + r)*Dn + lane16;
#pragma unroll
      for (int dfi = 0; dfi < 4; ++dfi) orow[dfi*16] = o[qi*4 + dfi][r] * li;
    }
}

extern "C" void kernel_launch(void* const* d_in, const int* in_sizes, int n_in,
                              void* d_out, int out_size, void* d_ws, size_t ws_size,
                              hipStream_t stream) {
  const float* q      = (const float*)d_in[0];
  const float* k      = (const float*)d_in[1];
  const float* v      = (const float*)d_in[2];
  const float* ratio  = (const float*)d_in[3];
  const float* scalep = (const float*)d_in[4];
  const void*  mask   = d_in[5];
  float* out = (float*)d_out;
  char* ws = (char*)d_ws;

  if (ws_size < WS_REQ) return;

  float* maskadd = (float*)(ws + WS_MASK_OFF);
  unsigned short* kbf = (unsigned short*)(ws + WS_K_OFF);
  unsigned short* vtb = (unsigned short*)(ws + WS_VT_OFF);

  hipLaunchKernelGGL(mask_prep_kernel, dim3(1), dim3(1024), 0, stream, mask, maskadd);
  hipLaunchKernelGGL(conv_k_kernel, dim3(Bn*LKn*Dn/8/256), dim3(256), 0, stream, k, kbf);
  hipLaunchKernelGGL(conv_vt_kernel, dim3(LKn/64, Dn/64, Bn), dim3(256), 0, stream, v, vtb);
  hipLaunchKernelGGL(attn_kernel, dim3(Bn*(LQn/64)), dim3(512), 0, stream,
                     q, kbf, vtb, ratio, scalep, maskadd, out);
}